// Round 2
// baseline (698.325 us; speedup 1.0000x reference)
//
#include <hip/hip_runtime.h>
#include <math.h>

#define NEG_SLOPE 0.2f
#define NXCD 8

// ---------------------------------------------------------------------------
// Register-tiled GEMM + fused attention logits.
//   H[n,64] = X[n,K] @ W[K,64];  As[n] = H.att_s;  Ad[n] = H.att_d
// Block: 256 threads -> tile 64 nodes x 64 features, per-thread 4x4 acc.
// ---------------------------------------------------------------------------
template <int K>
__global__ __launch_bounds__(256) void gemm_tile(
    const float* __restrict__ X, const float* __restrict__ W,
    const float* __restrict__ att_s, const float* __restrict__ att_d,
    float* __restrict__ H, float* __restrict__ As, float* __restrict__ Ad,
    int n)
{
    constexpr int XP = K + 4;
    constexpr int BK = 64;
    __shared__ float Xs[64 * XP];
    __shared__ float Ws[BK * 64];

    const int tid = threadIdx.x;
    const int node0 = blockIdx.x * 64;

    for (int i4 = tid; i4 < 64 * (K / 4); i4 += 256) {
        int r = i4 / (K / 4);
        int c = (i4 % (K / 4)) * 4;
        int nd = node0 + r;
        float4 v = make_float4(0.f, 0.f, 0.f, 0.f);
        if (nd < n) v = *(const float4*)&X[(size_t)nd * K + c];
        *(float4*)&Xs[r * XP + c] = v;
    }

    const int tx = tid & 15;   // feature group
    const int ty = tid >> 4;   // node group

    float acc[4][4];
#pragma unroll
    for (int r = 0; r < 4; ++r)
#pragma unroll
        for (int f = 0; f < 4; ++f) acc[r][f] = 0.0f;

    for (int kc = 0; kc < K; kc += BK) {
        __syncthreads();
        for (int i = tid; i < BK * 64; i += 256) Ws[i] = W[kc * 64 + i];
        __syncthreads();

        for (int k = 0; k < BK; k += 4) {
            float4 a0 = *(const float4*)&Xs[(ty * 4 + 0) * XP + kc + k];
            float4 a1 = *(const float4*)&Xs[(ty * 4 + 1) * XP + kc + k];
            float4 a2 = *(const float4*)&Xs[(ty * 4 + 2) * XP + kc + k];
            float4 a3 = *(const float4*)&Xs[(ty * 4 + 3) * XP + kc + k];
            float4 b0 = *(const float4*)&Ws[(k + 0) * 64 + tx * 4];
            float4 b1 = *(const float4*)&Ws[(k + 1) * 64 + tx * 4];
            float4 b2 = *(const float4*)&Ws[(k + 2) * 64 + tx * 4];
            float4 b3 = *(const float4*)&Ws[(k + 3) * 64 + tx * 4];
#define GEMM_ROW(rr, av)                                                     \
            acc[rr][0] = fmaf(av.x, b0.x, acc[rr][0]);                       \
            acc[rr][1] = fmaf(av.x, b0.y, acc[rr][1]);                       \
            acc[rr][2] = fmaf(av.x, b0.z, acc[rr][2]);                       \
            acc[rr][3] = fmaf(av.x, b0.w, acc[rr][3]);                       \
            acc[rr][0] = fmaf(av.y, b1.x, acc[rr][0]);                       \
            acc[rr][1] = fmaf(av.y, b1.y, acc[rr][1]);                       \
            acc[rr][2] = fmaf(av.y, b1.z, acc[rr][2]);                       \
            acc[rr][3] = fmaf(av.y, b1.w, acc[rr][3]);                       \
            acc[rr][0] = fmaf(av.z, b2.x, acc[rr][0]);                       \
            acc[rr][1] = fmaf(av.z, b2.y, acc[rr][1]);                       \
            acc[rr][2] = fmaf(av.z, b2.z, acc[rr][2]);                       \
            acc[rr][3] = fmaf(av.z, b2.w, acc[rr][3]);                       \
            acc[rr][0] = fmaf(av.w, b3.x, acc[rr][0]);                       \
            acc[rr][1] = fmaf(av.w, b3.y, acc[rr][1]);                       \
            acc[rr][2] = fmaf(av.w, b3.z, acc[rr][2]);                       \
            acc[rr][3] = fmaf(av.w, b3.w, acc[rr][3]);
            GEMM_ROW(0, a0)
            GEMM_ROW(1, a1)
            GEMM_ROW(2, a2)
            GEMM_ROW(3, a3)
#undef GEMM_ROW
        }
    }

    float4 ats = *(const float4*)&att_s[tx * 4];
    float4 atd = *(const float4*)&att_d[tx * 4];
#pragma unroll
    for (int rr = 0; rr < 4; ++rr) {
        int nd = node0 + ty * 4 + rr;
        float vs = acc[rr][0] * ats.x + acc[rr][1] * ats.y +
                   acc[rr][2] * ats.z + acc[rr][3] * ats.w;
        float vd = acc[rr][0] * atd.x + acc[rr][1] * atd.y +
                   acc[rr][2] * atd.z + acc[rr][3] * atd.w;
#pragma unroll
        for (int off = 8; off; off >>= 1) {
            vs += __shfl_xor(vs, off);
            vd += __shfl_xor(vd, off);
        }
        if (nd < n) {
            float4 hv = make_float4(acc[rr][0], acc[rr][1], acc[rr][2], acc[rr][3]);
            *(float4*)&H[(size_t)nd * 64 + tx * 4] = hv;
            if (tx == 0) { As[nd] = vs; Ad[nd] = vd; }
        }
    }
}

// ---------------------------------------------------------------------------
// Phase 1: fused degree-histogram + XCD-range bucketing (counting sort, pass 1)
// Each block owns a contiguous edge chunk. Pass A: per-thread register bucket
// counts + global deg histogram. One global atomic per (block, bucket) reserves
// space. Pass B: re-read chunk (L1-hot), wave-ballot compaction, write 4B
// packed records (dlocal << 17 | src) contiguously into 8 bucket regions.
// Requires n <= 131072 and lo_div < 32768 (holds: n=100000, lo_div=12500).
// ---------------------------------------------------------------------------
__global__ __launch_bounds__(256) void bucket_kernel(
    const int* __restrict__ src, const int* __restrict__ dst, int e,
    int* __restrict__ deg, int* __restrict__ bkt_cnt /* stride 32 ints */,
    unsigned* __restrict__ bkt, int lo_div, int cap)
{
    __shared__ int cnt[NXCD];
    __shared__ int off[NXCD];
    const int tid = threadIdx.x;
    const int lane = tid & 63;
    const int chunk = (e + gridDim.x - 1) / gridDim.x;
    const int beg = blockIdx.x * chunk;
    const int end = min(beg + chunk, e);

    if (tid < NXCD) cnt[tid] = 0;
    __syncthreads();

    // ---- pass A: count buckets (registers) + deg histogram ----
    int c[NXCD];
#pragma unroll
    for (int j = 0; j < NXCD; ++j) c[j] = 0;

    for (int i = beg + tid; i < end; i += 256) {
        int d = dst[i];
        atomicAdd(&deg[d], 1);
        unsigned b = (unsigned)d / (unsigned)lo_div;
#pragma unroll
        for (int j = 0; j < NXCD; ++j) c[j] += (b == (unsigned)j);
    }
#pragma unroll
    for (int j = 0; j < NXCD; ++j) {
        int v = c[j];
#pragma unroll
        for (int o = 32; o; o >>= 1) v += __shfl_xor(v, o);
        if (lane == 0) atomicAdd(&cnt[j], v);
    }
    __syncthreads();

    if (tid < NXCD)
        off[tid] = tid * cap + atomicAdd(&bkt_cnt[tid * 32], cnt[tid]);
    __syncthreads();

    // ---- pass B: ballot-compacted bucket writes ----
    const unsigned long long ltmask = (1ull << lane) - 1ull;
    for (int i = beg + tid; i < end; i += 256) {
        int d = dst[i];
        int s = src[i];
        unsigned b = (unsigned)d / (unsigned)lo_div;
#pragma unroll
        for (int j = 0; j < NXCD; ++j) {
            unsigned long long m = __ballot(b == (unsigned)j);
            if (m) {
                int leader = __ffsll((unsigned long long)m) - 1;
                int basej = 0;
                if (lane == leader) basej = atomicAdd(&off[j], __popcll(m));
                basej = __shfl(basej, leader);
                if (b == (unsigned)j) {
                    int pos = basej + __popcll(m & ltmask);
                    if (pos < (j + 1) * cap)
                        bkt[pos] = ((unsigned)(d - j * lo_div) << 17) | (unsigned)s;
                }
            }
        }
    }
}

#define SCAN_B 256
#define SCAN_E 1024  // 4 elems per thread

__global__ __launch_bounds__(SCAN_B) void scan1_kernel(
    const int* __restrict__ deg, int n, int* __restrict__ out /* = rp+1 */,
    int* __restrict__ partials)
{
    __shared__ int sh[SCAN_B];
    const int b = blockIdx.x, t = threadIdx.x;
    const int base = b * SCAN_E + t * 4;
    int v[4];
#pragma unroll
    for (int i = 0; i < 4; ++i) {
        int idx = base + i;
        v[i] = (idx < n) ? deg[idx] : 0;
    }
    v[1] += v[0]; v[2] += v[1]; v[3] += v[2];
    sh[t] = v[3];
    __syncthreads();
    for (int off = 1; off < SCAN_B; off <<= 1) {
        int x = (t >= off) ? sh[t - off] : 0;
        __syncthreads();
        sh[t] += x;
        __syncthreads();
    }
    int excl = (t > 0) ? sh[t - 1] : 0;
#pragma unroll
    for (int i = 0; i < 4; ++i) {
        int idx = base + i;
        if (idx < n) out[idx] = v[i] + excl;  // inclusive scan
    }
    if (t == SCAN_B - 1) partials[b] = sh[t];
}

// parallel single-block exclusive scan of partials (nb <= 256)
__global__ __launch_bounds__(256) void scan2_kernel(int* __restrict__ partials, int nb)
{
    __shared__ int sh[256];
    const int t = threadIdx.x;
    int v = (t < nb) ? partials[t] : 0;
    sh[t] = v;
    __syncthreads();
    for (int off = 1; off < 256; off <<= 1) {
        int x = (t >= off) ? sh[t - off] : 0;
        __syncthreads();
        sh[t] += x;
        __syncthreads();
    }
    if (t < nb) partials[t] = (t > 0) ? sh[t - 1] : 0;  // exclusive
}

// adds block offsets; also initializes cursor[] = final rp[]
__global__ void scan3_kernel(int* __restrict__ rp, int* __restrict__ cursor,
                             int n, const int* __restrict__ partials)
{
    int i = blockIdx.x * blockDim.x + threadIdx.x;
    if (i < n) {
        int v = rp[1 + i] + partials[i >> 10];
        rp[1 + i] = v;
        if (i + 1 < n) cursor[i + 1] = v;
    }
    if (i == 0) { rp[0] = 0; cursor[0] = 0; }
}

// ---------------------------------------------------------------------------
// Phase 2: per-XCD fine scatter. Group g streams ONLY its own ~0.8MB bucket
// (instead of the full 12.8MB edge list), so its 1.6MB rec region stays
// L2-resident and writebacks are full lines.
// ---------------------------------------------------------------------------
__global__ __launch_bounds__(256) void scatter2_kernel(
    const unsigned* __restrict__ bkt, const int* __restrict__ bkt_cnt,
    int* __restrict__ cursor, int2* __restrict__ rec,
    const float* __restrict__ As, const float* __restrict__ Ad,
    int lo_div, int cap)
{
    const int g = blockIdx.x & (NXCD - 1);
    const int gi = blockIdx.x >> 3;
    const int nblk = gridDim.x >> 3;
    const int cnt = min(bkt_cnt[g * 32], cap);
    const int base = g * cap;
    const int dbase = g * lo_div;

    for (int i = gi * 256 + threadIdx.x; i < cnt; i += nblk * 256) {
        unsigned v = __builtin_nontemporal_load(&bkt[base + i]);
        int s = (int)(v & 0x1FFFFu);
        int d = dbase + (int)(v >> 17);
        float ev = As[s] + Ad[d];
        ev = (ev >= 0.0f) ? ev : NEG_SLOPE * ev;
        int pos = atomicAdd(&cursor[d], 1);
        int2 r;
        r.x = s;
        r.y = __float_as_int(ev);
        rec[pos] = r;
    }
}

// ---------------------------------------------------------------------------
// Aggregation: one wave per destination node, XCD-swizzled to match the
// scatter's range->XCD mapping.
// Pass A: online softmax over coalesced rec[].y.
// Pass B: weighted gather of H rows, 4 independent accumulator chains.
// ---------------------------------------------------------------------------
__global__ __launch_bounds__(256) void aggr_kernel(
    const int* __restrict__ rp, const int2* __restrict__ rec,
    const float* __restrict__ Hin, const float* __restrict__ bias,
    float* __restrict__ Out, int n, int lo_div, int relu_flag)
{
    const int lane = threadIdx.x & 63;
    const int wv = threadIdx.x >> 6;
    const float b = bias[lane];

    const int g = blockIdx.x & (NXCD - 1);
    const int gi = blockIdx.x >> 3;
    const int ngb = gridDim.x >> 3;
    const int lo = g * lo_div;
    const int hi = min(lo + lo_div, n);

    for (int d = lo + gi * 4 + wv; d < hi; d += ngb * 4) {
        const int beg = rp[d], end = rp[d + 1];

        // online max+sum (sentinel avoids -inf - -inf NaN)
        float m = -1e30f, s = 0.0f;
        for (int i = beg + lane; i < end; i += 64) {
            float e = __int_as_float(rec[i].y);
            float mn = fmaxf(m, e);
            s = s * __expf(m - mn) + __expf(e - mn);
            m = mn;
        }
#pragma unroll
        for (int off = 32; off; off >>= 1) {
            float mo = __shfl_xor(m, off);
            float so = __shfl_xor(s, off);
            float mn = fmaxf(m, mo);
            s = s * __expf(m - mn) + so * __expf(mo - mn);
            m = mn;
        }
        const float inv = 1.0f / (s + 1e-16f);

        float acc0 = 0.f, acc1 = 0.f, acc2 = 0.f, acc3 = 0.f;
        int i = beg;
        for (; i + 4 <= end; i += 4) {
            int2 r0 = rec[i + 0];
            int2 r1 = rec[i + 1];
            int2 r2 = rec[i + 2];
            int2 r3 = rec[i + 3];
            float w0 = __expf(__int_as_float(r0.y) - m) * inv;
            float w1 = __expf(__int_as_float(r1.y) - m) * inv;
            float w2 = __expf(__int_as_float(r2.y) - m) * inv;
            float w3 = __expf(__int_as_float(r3.y) - m) * inv;
            acc0 = fmaf(w0, Hin[(size_t)r0.x * 64 + lane], acc0);
            acc1 = fmaf(w1, Hin[(size_t)r1.x * 64 + lane], acc1);
            acc2 = fmaf(w2, Hin[(size_t)r2.x * 64 + lane], acc2);
            acc3 = fmaf(w3, Hin[(size_t)r3.x * 64 + lane], acc3);
        }
        for (; i < end; ++i) {
            int2 r = rec[i];
            float w = __expf(__int_as_float(r.y) - m) * inv;
            acc0 = fmaf(w, Hin[(size_t)r.x * 64 + lane], acc0);
        }

        float r = (acc0 + acc1) + (acc2 + acc3) + b;
        if (relu_flag) r = fmaxf(r, 0.0f);
        Out[(size_t)d * 64 + lane] = r;
    }
}

// ---------------------------------------------------------------------------
// Final linear [64 -> 32] + log_softmax. 2 nodes per wave.
// ---------------------------------------------------------------------------
__global__ __launch_bounds__(256) void lin_lsm_kernel(
    const float* __restrict__ Z, const float* __restrict__ Wl,
    const float* __restrict__ bl, float* __restrict__ out, int n)
{
    __shared__ float Ws[64 * 32];
    __shared__ float bs[32];
    for (int i = threadIdx.x; i < 64 * 32; i += 256) Ws[i] = Wl[i];
    if (threadIdx.x < 32) bs[threadIdx.x] = bl[threadIdx.x];
    __syncthreads();

    const int lane = threadIdx.x & 63;
    const int wv = threadIdx.x >> 6;
    const int half = lane >> 5;
    const int o = lane & 31;

    for (int base = (blockIdx.x * 4 + wv) * 2; base < n; base += gridDim.x * 8) {
        const int nd = base + half;
        float acc = 0.0f;
        if (nd < n) {
            const float* z = Z + (size_t)nd * 64;
#pragma unroll
            for (int k = 0; k < 64; ++k)
                acc = fmaf(z[k], Ws[k * 32 + o], acc);
            acc += bs[o];
        }
        float m = acc;
#pragma unroll
        for (int off = 16; off; off >>= 1) m = fmaxf(m, __shfl_xor(m, off, 32));
        float ex = __expf(acc - m);
        float s = ex;
#pragma unroll
        for (int off = 16; off; off >>= 1) s += __shfl_xor(s, off, 32);
        if (nd < n) out[(size_t)nd * 32 + o] = acc - m - logf(s);
    }
}

// ---------------------------------------------------------------------------
extern "C" void kernel_launch(void* const* d_in, const int* in_sizes, int n_in,
                              void* d_out, int out_size, void* d_ws, size_t ws_size,
                              hipStream_t stream)
{
    const float* x        = (const float*)d_in[0];
    const int*   ei1      = (const int*)d_in[1];
    const int*   ei2      = (const int*)d_in[2];
    const float* W1       = (const float*)d_in[3];
    const float* att_src1 = (const float*)d_in[4];
    const float* att_dst1 = (const float*)d_in[5];
    const float* b1       = (const float*)d_in[6];
    const float* W2       = (const float*)d_in[7];
    const float* att_src2 = (const float*)d_in[8];
    const float* att_dst2 = (const float*)d_in[9];
    const float* b2       = (const float*)d_in[10];
    const float* Wlin     = (const float*)d_in[11];
    const float* blin     = (const float*)d_in[12];
    float* out = (float*)d_out;

    const int n = in_sizes[0] / 128;   // 100000
    const int e = in_sizes[1] / 2;     // 1600000

    size_t off = 0;
    auto alloc = [&](size_t bytes) {
        void* p = (char*)d_ws + off;
        off += (bytes + 255) & ~(size_t)255;
        return p;
    };
    float* bufH  = (float*)alloc((size_t)n * 64 * 4);
    float* bufZ  = (float*)alloc((size_t)n * 64 * 4);
    float* As    = (float*)alloc((size_t)n * 4);
    float* Ad    = (float*)alloc((size_t)n * 4);
    int* deg     = (int*)alloc((size_t)(n + 256) * 4);  // +256: bkt_cnt (8 x stride 32)
    int* rp      = (int*)alloc((size_t)(n + 1) * 4);
    int* cursor  = (int*)alloc((size_t)n * 4);
    int* partials= (int*)alloc(256 * 4);
    int2* rec    = (int2*)alloc((size_t)e * 8);

    int* bktc = deg + n;                  // 8 counters, stride 32 ints (128B apart)
    const int lo_div = (n + NXCD - 1) / NXCD;
    const int cap = e / NXCD + 8192;      // 19-sigma slack for uniform-random dst
    unsigned* bkt = (unsigned*)bufZ;      // bucket array overlays bufZ (dead here)

    const int nb_scan = (n + SCAN_E - 1) / SCAN_E;
    const int gN = (n + 255) / 256;
    const int gTile = (n + 63) / 64;
    const int gAggr = NXCD * ((lo_div + 3) / 4);
    const int gBkt  = 2048;  // edge chunk ~782/block
    const int gScat = 2048;  // multiple of 8; 256 blocks/XCD-group

    // ---------------- Layer 1 ----------------
    gemm_tile<128><<<gTile, 256, 0, stream>>>(x, W1, att_src1, att_dst1, bufH, As, Ad, n);

    hipMemsetAsync(deg, 0, (size_t)(n + 256) * 4, stream);
    bucket_kernel<<<gBkt, 256, 0, stream>>>(ei1, ei1 + e, e, deg, bktc, bkt, lo_div, cap);
    scan1_kernel<<<nb_scan, SCAN_B, 0, stream>>>(deg, n, rp + 1, partials);
    scan2_kernel<<<1, 256, 0, stream>>>(partials, nb_scan);
    scan3_kernel<<<gN, 256, 0, stream>>>(rp, cursor, n, partials);
    scatter2_kernel<<<gScat, 256, 0, stream>>>(bkt, bktc, cursor, rec, As, Ad, lo_div, cap);

    aggr_kernel<<<gAggr, 256, 0, stream>>>(rp, rec, bufH, b1, bufZ, n, lo_div, 1);

    // ---------------- Layer 2 ----------------
    gemm_tile<64><<<gTile, 256, 0, stream>>>(bufZ, W2, att_src2, att_dst2, bufH, As, Ad, n);

    hipMemsetAsync(deg, 0, (size_t)(n + 256) * 4, stream);
    bucket_kernel<<<gBkt, 256, 0, stream>>>(ei2, ei2 + e, e, deg, bktc, bkt, lo_div, cap);
    scan1_kernel<<<nb_scan, SCAN_B, 0, stream>>>(deg, n, rp + 1, partials);
    scan2_kernel<<<1, 256, 0, stream>>>(partials, nb_scan);
    scan3_kernel<<<gN, 256, 0, stream>>>(rp, cursor, n, partials);
    scatter2_kernel<<<gScat, 256, 0, stream>>>(bkt, bktc, cursor, rec, As, Ad, lo_div, cap);

    aggr_kernel<<<gAggr, 256, 0, stream>>>(rp, rec, bufH, b2, bufZ, n, lo_div, 0);

    // ---------------- Final linear + log_softmax ----------------
    const int gLSM = (n + 7) / 8;
    lin_lsm_kernel<<<gLSM, 256, 0, stream>>>(bufZ, Wlin, blin, out, n);
}

// Round 3
// 480.021 us; speedup vs baseline: 1.4548x; 1.4548x over previous
//
#include <hip/hip_runtime.h>
#include <math.h>

#define NEG_SLOPE 0.2f
#define NXCD 8
#define SUBCAP 8960   // per-sub-bucket record capacity (mean 8192, sigma~90 -> 8.5 sigma slack)

// ---------------------------------------------------------------------------
// Register-tiled GEMM + fused attention logits.
//   H[n,64] = X[n,K] @ W[K,64];  As[n] = H.att_s;  Ad[n] = H.att_d
// Block: 256 threads -> tile 64 nodes x 64 features, per-thread 4x4 acc.
// ---------------------------------------------------------------------------
template <int K>
__global__ __launch_bounds__(256) void gemm_tile(
    const float* __restrict__ X, const float* __restrict__ W,
    const float* __restrict__ att_s, const float* __restrict__ att_d,
    float* __restrict__ H, float* __restrict__ As, float* __restrict__ Ad,
    int n)
{
    constexpr int XP = K + 4;
    constexpr int BK = 64;
    __shared__ float Xs[64 * XP];
    __shared__ float Ws[BK * 64];

    const int tid = threadIdx.x;
    const int node0 = blockIdx.x * 64;

    for (int i4 = tid; i4 < 64 * (K / 4); i4 += 256) {
        int r = i4 / (K / 4);
        int c = (i4 % (K / 4)) * 4;
        int nd = node0 + r;
        float4 v = make_float4(0.f, 0.f, 0.f, 0.f);
        if (nd < n) v = *(const float4*)&X[(size_t)nd * K + c];
        *(float4*)&Xs[r * XP + c] = v;
    }

    const int tx = tid & 15;   // feature group
    const int ty = tid >> 4;   // node group

    float acc[4][4];
#pragma unroll
    for (int r = 0; r < 4; ++r)
#pragma unroll
        for (int f = 0; f < 4; ++f) acc[r][f] = 0.0f;

    for (int kc = 0; kc < K; kc += BK) {
        __syncthreads();
        for (int i = tid; i < BK * 64; i += 256) Ws[i] = W[kc * 64 + i];
        __syncthreads();

        for (int k = 0; k < BK; k += 4) {
            float4 a0 = *(const float4*)&Xs[(ty * 4 + 0) * XP + kc + k];
            float4 a1 = *(const float4*)&Xs[(ty * 4 + 1) * XP + kc + k];
            float4 a2 = *(const float4*)&Xs[(ty * 4 + 2) * XP + kc + k];
            float4 a3 = *(const float4*)&Xs[(ty * 4 + 3) * XP + kc + k];
            float4 b0 = *(const float4*)&Ws[(k + 0) * 64 + tx * 4];
            float4 b1 = *(const float4*)&Ws[(k + 1) * 64 + tx * 4];
            float4 b2 = *(const float4*)&Ws[(k + 2) * 64 + tx * 4];
            float4 b3 = *(const float4*)&Ws[(k + 3) * 64 + tx * 4];
#define GEMM_ROW(rr, av)                                                     \
            acc[rr][0] = fmaf(av.x, b0.x, acc[rr][0]);                       \
            acc[rr][1] = fmaf(av.x, b0.y, acc[rr][1]);                       \
            acc[rr][2] = fmaf(av.x, b0.z, acc[rr][2]);                       \
            acc[rr][3] = fmaf(av.x, b0.w, acc[rr][3]);                       \
            acc[rr][0] = fmaf(av.y, b1.x, acc[rr][0]);                       \
            acc[rr][1] = fmaf(av.y, b1.y, acc[rr][1]);                       \
            acc[rr][2] = fmaf(av.y, b1.z, acc[rr][2]);                       \
            acc[rr][3] = fmaf(av.y, b1.w, acc[rr][3]);                       \
            acc[rr][0] = fmaf(av.z, b2.x, acc[rr][0]);                       \
            acc[rr][1] = fmaf(av.z, b2.y, acc[rr][1]);                       \
            acc[rr][2] = fmaf(av.z, b2.z, acc[rr][2]);                       \
            acc[rr][3] = fmaf(av.z, b2.w, acc[rr][3]);                       \
            acc[rr][0] = fmaf(av.w, b3.x, acc[rr][0]);                       \
            acc[rr][1] = fmaf(av.w, b3.y, acc[rr][1]);                       \
            acc[rr][2] = fmaf(av.w, b3.z, acc[rr][2]);                       \
            acc[rr][3] = fmaf(av.w, b3.w, acc[rr][3]);
            GEMM_ROW(0, a0)
            GEMM_ROW(1, a1)
            GEMM_ROW(2, a2)
            GEMM_ROW(3, a3)
#undef GEMM_ROW
        }
    }

    float4 ats = *(const float4*)&att_s[tx * 4];
    float4 atd = *(const float4*)&att_d[tx * 4];
#pragma unroll
    for (int rr = 0; rr < 4; ++rr) {
        int nd = node0 + ty * 4 + rr;
        float vs = acc[rr][0] * ats.x + acc[rr][1] * ats.y +
                   acc[rr][2] * ats.z + acc[rr][3] * ats.w;
        float vd = acc[rr][0] * atd.x + acc[rr][1] * atd.y +
                   acc[rr][2] * atd.z + acc[rr][3] * atd.w;
#pragma unroll
        for (int off = 8; off; off >>= 1) {
            vs += __shfl_xor(vs, off);
            vd += __shfl_xor(vd, off);
        }
        if (nd < n) {
            float4 hv = make_float4(acc[rr][0], acc[rr][1], acc[rr][2], acc[rr][3]);
            *(float4*)&H[(size_t)nd * 64 + tx * 4] = hv;
            if (tx == 0) { As[nd] = vs; Ad[nd] = vd; }
        }
    }
}

// ---------------------------------------------------------------------------
// Level 1: fine bucketing into sub-buckets of 512 dst nodes (sub = d >> 9).
// LDS histogram + one global atomic per (block, sub-bucket) reservation +
// LDS-cursor compacted writes of 4B packed records ((d&511)<<17 | src).
// ZERO per-edge global atomics. Requires n <= 131072 (nsub <= 256) and
// src < 2^17 (n=100000 ok).
// ---------------------------------------------------------------------------
__global__ __launch_bounds__(256) void fbucket_kernel(
    const int* __restrict__ src, const int* __restrict__ dst, int e,
    int* __restrict__ gcnt /* stride 16 ints */, unsigned* __restrict__ bkt)
{
    __shared__ int cnt[256];
    __shared__ int off[256];
    const int tid = threadIdx.x;
    const int chunk = (e + gridDim.x - 1) / gridDim.x;
    const int beg = blockIdx.x * chunk;
    const int end = min(beg + chunk, e);

    cnt[tid] = 0;
    __syncthreads();

    // pass A: LDS sub-bucket histogram
    for (int i = beg + tid; i < end; i += 256)
        atomicAdd(&cnt[dst[i] >> 9], 1);
    __syncthreads();

    // per-(block, sub) reservation: one global atomic each (64B-padded counters)
    {
        int c = cnt[tid];
        off[tid] = tid * SUBCAP + (c ? atomicAdd(&gcnt[tid * 16], c) : 0);
    }
    __syncthreads();

    // pass B: LDS-cursor compacted writes (chunk is L2-hot from pass A)
    for (int i = beg + tid; i < end; i += 256) {
        int d = dst[i];
        int s = src[i];
        int sub = d >> 9;
        int pos = atomicAdd(&off[sub], 1);
        if (pos < (sub + 1) * SUBCAP)
            bkt[pos] = ((unsigned)(d & 511) << 17) | (unsigned)s;
    }
}

// ---------------------------------------------------------------------------
// Level 2: one block per sub-bucket. Load records to LDS, LDS histogram over
// 512 node counters, block-wide exclusive scan, LDS-cursor placement ->
// dst-sorted rec (ev computed here; Ad slice in LDS) + per-node (beg,end).
// Zero global atomics; block exclusively owns its 70KB rec region -> L2
// write-combining is perfect (every line fully written).
// ---------------------------------------------------------------------------
__global__ __launch_bounds__(256) void sort3_kernel(
    const unsigned* __restrict__ bkt, const int* __restrict__ gcnt,
    const float* __restrict__ As, const float* __restrict__ Ad,
    int2* __restrict__ rec, int2* __restrict__ rpBE, int n)
{
    __shared__ unsigned recs[SUBCAP];  // 35840 B
    __shared__ int hist[512];          // counts -> exclusive offsets -> cursors
    __shared__ float AdS[512];
    __shared__ int sh[256];

    const int b = blockIdx.x;
    const int tid = threadIdx.x;
    const int base = b * SUBCAP;
    const int cnt = min(gcnt[b * 16], SUBCAP);

    for (int t = tid; t < 512; t += 256) {
        hist[t] = 0;
        int d = (b << 9) + t;
        AdS[t] = (d < n) ? Ad[d] : 0.0f;
    }
    __syncthreads();

    // load + histogram
    for (int i = tid; i < cnt; i += 256) {
        unsigned v = bkt[base + i];
        recs[i] = v;
        atomicAdd(&hist[v >> 17], 1);
    }
    __syncthreads();

    // 512-entry exclusive scan (2 elems/thread)
    int a0 = hist[2 * tid];
    int a1 = hist[2 * tid + 1];
    sh[tid] = a0 + a1;
    __syncthreads();
    for (int off = 1; off < 256; off <<= 1) {
        int x = (tid >= off) ? sh[tid - off] : 0;
        __syncthreads();
        sh[tid] += x;
        __syncthreads();
    }
    int ex = (tid > 0) ? sh[tid - 1] : 0;
    hist[2 * tid]     = ex;            // becomes placement cursor
    hist[2 * tid + 1] = ex + a0;
    {
        int d0 = (b << 9) + 2 * tid;
        if (d0 < n)     rpBE[d0]     = make_int2(base + ex,          base + ex + a0);
        if (d0 + 1 < n) rpBE[d0 + 1] = make_int2(base + ex + a0,     base + ex + a0 + a1);
    }
    __syncthreads();

    // placement: sorted rec with fused leaky-relu logit
    for (int i = tid; i < cnt; i += 256) {
        unsigned v = recs[i];
        int dl = (int)(v >> 17);
        int s  = (int)(v & 0x1FFFFu);
        int pos = atomicAdd(&hist[dl], 1);
        float ev = As[s] + AdS[dl];
        ev = (ev >= 0.0f) ? ev : NEG_SLOPE * ev;
        rec[base + pos] = make_int2(s, __float_as_int(ev));
    }
}

// ---------------------------------------------------------------------------
// Aggregation: one wave per destination node, XCD-swizzled dst partition.
// Pass A: online softmax over coalesced rec[].y.
// Pass B: weighted gather of H rows, 4 independent accumulator chains.
// ---------------------------------------------------------------------------
__global__ __launch_bounds__(256) void aggr_kernel(
    const int2* __restrict__ rpBE, const int2* __restrict__ rec,
    const float* __restrict__ Hin, const float* __restrict__ bias,
    float* __restrict__ Out, int n, int lo_div, int relu_flag)
{
    const int lane = threadIdx.x & 63;
    const int wv = threadIdx.x >> 6;
    const float b = bias[lane];

    const int g = blockIdx.x & (NXCD - 1);
    const int gi = blockIdx.x >> 3;
    const int ngb = gridDim.x >> 3;
    const int lo = g * lo_div;
    const int hi = min(lo + lo_div, n);

    for (int d = lo + gi * 4 + wv; d < hi; d += ngb * 4) {
        const int2 be = rpBE[d];
        const int beg = be.x, end = be.y;

        // online max+sum (sentinel avoids -inf - -inf NaN)
        float m = -1e30f, s = 0.0f;
        for (int i = beg + lane; i < end; i += 64) {
            float e = __int_as_float(rec[i].y);
            float mn = fmaxf(m, e);
            s = s * __expf(m - mn) + __expf(e - mn);
            m = mn;
        }
#pragma unroll
        for (int off = 32; off; off >>= 1) {
            float mo = __shfl_xor(m, off);
            float so = __shfl_xor(s, off);
            float mn = fmaxf(m, mo);
            s = s * __expf(m - mn) + so * __expf(mo - mn);
            m = mn;
        }
        const float inv = 1.0f / (s + 1e-16f);

        float acc0 = 0.f, acc1 = 0.f, acc2 = 0.f, acc3 = 0.f;
        int i = beg;
        for (; i + 4 <= end; i += 4) {
            int2 r0 = rec[i + 0];
            int2 r1 = rec[i + 1];
            int2 r2 = rec[i + 2];
            int2 r3 = rec[i + 3];
            float w0 = __expf(__int_as_float(r0.y) - m) * inv;
            float w1 = __expf(__int_as_float(r1.y) - m) * inv;
            float w2 = __expf(__int_as_float(r2.y) - m) * inv;
            float w3 = __expf(__int_as_float(r3.y) - m) * inv;
            acc0 = fmaf(w0, Hin[(size_t)r0.x * 64 + lane], acc0);
            acc1 = fmaf(w1, Hin[(size_t)r1.x * 64 + lane], acc1);
            acc2 = fmaf(w2, Hin[(size_t)r2.x * 64 + lane], acc2);
            acc3 = fmaf(w3, Hin[(size_t)r3.x * 64 + lane], acc3);
        }
        for (; i < end; ++i) {
            int2 r = rec[i];
            float w = __expf(__int_as_float(r.y) - m) * inv;
            acc0 = fmaf(w, Hin[(size_t)r.x * 64 + lane], acc0);
        }

        float r = (acc0 + acc1) + (acc2 + acc3) + b;
        if (relu_flag) r = fmaxf(r, 0.0f);
        Out[(size_t)d * 64 + lane] = r;
    }
}

// ---------------------------------------------------------------------------
// Final linear [64 -> 32] + log_softmax. 2 nodes per wave.
// ---------------------------------------------------------------------------
__global__ __launch_bounds__(256) void lin_lsm_kernel(
    const float* __restrict__ Z, const float* __restrict__ Wl,
    const float* __restrict__ bl, float* __restrict__ out, int n)
{
    __shared__ float Ws[64 * 32];
    __shared__ float bs[32];
    for (int i = threadIdx.x; i < 64 * 32; i += 256) Ws[i] = Wl[i];
    if (threadIdx.x < 32) bs[threadIdx.x] = bl[threadIdx.x];
    __syncthreads();

    const int lane = threadIdx.x & 63;
    const int wv = threadIdx.x >> 6;
    const int half = lane >> 5;
    const int o = lane & 31;

    for (int base = (blockIdx.x * 4 + wv) * 2; base < n; base += gridDim.x * 8) {
        const int nd = base + half;
        float acc = 0.0f;
        if (nd < n) {
            const float* z = Z + (size_t)nd * 64;
#pragma unroll
            for (int k = 0; k < 64; ++k)
                acc = fmaf(z[k], Ws[k * 32 + o], acc);
            acc += bs[o];
        }
        float m = acc;
#pragma unroll
        for (int off = 16; off; off >>= 1) m = fmaxf(m, __shfl_xor(m, off, 32));
        float ex = __expf(acc - m);
        float s = ex;
#pragma unroll
        for (int off = 16; off; off >>= 1) s += __shfl_xor(s, off, 32);
        if (nd < n) out[(size_t)nd * 32 + o] = acc - m - logf(s);
    }
}

// ---------------------------------------------------------------------------
extern "C" void kernel_launch(void* const* d_in, const int* in_sizes, int n_in,
                              void* d_out, int out_size, void* d_ws, size_t ws_size,
                              hipStream_t stream)
{
    const float* x        = (const float*)d_in[0];
    const int*   ei1      = (const int*)d_in[1];
    const int*   ei2      = (const int*)d_in[2];
    const float* W1       = (const float*)d_in[3];
    const float* att_src1 = (const float*)d_in[4];
    const float* att_dst1 = (const float*)d_in[5];
    const float* b1       = (const float*)d_in[6];
    const float* W2       = (const float*)d_in[7];
    const float* att_src2 = (const float*)d_in[8];
    const float* att_dst2 = (const float*)d_in[9];
    const float* b2       = (const float*)d_in[10];
    const float* Wlin     = (const float*)d_in[11];
    const float* blin     = (const float*)d_in[12];
    float* out = (float*)d_out;

    const int n = in_sizes[0] / 128;   // 100000
    const int e = in_sizes[1] / 2;     // 1600000
    const int nsub = (n + 511) >> 9;   // 196 sub-buckets of 512 nodes

    size_t off = 0;
    auto alloc = [&](size_t bytes) {
        void* p = (char*)d_ws + off;
        off += (bytes + 255) & ~(size_t)255;
        return p;
    };
    float* bufH  = (float*)alloc((size_t)n * 64 * 4);
    float* bufZ  = (float*)alloc((size_t)n * 64 * 4);
    float* As    = (float*)alloc((size_t)n * 4);
    float* Ad    = (float*)alloc((size_t)n * 4);
    int2* rpBE   = (int2*)alloc((size_t)n * 8);
    int* gcnt    = (int*)alloc((size_t)256 * 16 * 4);      // 64B-padded counters
    int2* rec    = (int2*)alloc((size_t)nsub * SUBCAP * 8);

    unsigned* bkt = (unsigned*)bufZ;   // 7.0 MB packed records overlay bufZ (dead here)

    const int lo_div = (n + NXCD - 1) / NXCD;
    const int gTile = (n + 63) / 64;
    const int gAggr = NXCD * ((lo_div + 3) / 4);
    const int gBkt  = 512;             // chunk ~3125 edges/block

    // ---------------- Layer 1 ----------------
    gemm_tile<128><<<gTile, 256, 0, stream>>>(x, W1, att_src1, att_dst1, bufH, As, Ad, n);

    hipMemsetAsync(gcnt, 0, (size_t)256 * 16 * 4, stream);
    fbucket_kernel<<<gBkt, 256, 0, stream>>>(ei1, ei1 + e, e, gcnt, bkt);
    sort3_kernel<<<nsub, 256, 0, stream>>>(bkt, gcnt, As, Ad, rec, rpBE, n);
    aggr_kernel<<<gAggr, 256, 0, stream>>>(rpBE, rec, bufH, b1, bufZ, n, lo_div, 1);

    // ---------------- Layer 2 ----------------
    gemm_tile<64><<<gTile, 256, 0, stream>>>(bufZ, W2, att_src2, att_dst2, bufH, As, Ad, n);

    hipMemsetAsync(gcnt, 0, (size_t)256 * 16 * 4, stream);
    fbucket_kernel<<<gBkt, 256, 0, stream>>>(ei2, ei2 + e, e, gcnt, bkt);
    sort3_kernel<<<nsub, 256, 0, stream>>>(bkt, gcnt, As, Ad, rec, rpBE, n);
    aggr_kernel<<<gAggr, 256, 0, stream>>>(rpBE, rec, bufH, b2, bufZ, n, lo_div, 0);

    // ---------------- Final linear + log_softmax ----------------
    const int gLSM = (n + 7) / 8;
    lin_lsm_kernel<<<gLSM, 256, 0, stream>>>(bufZ, Wlin, blin, out, n);
}

// Round 13
// 447.909 us; speedup vs baseline: 1.5591x; 1.0717x over previous
//
#include <hip/hip_runtime.h>
#include <math.h>

#define NEG_SLOPE 0.2f
#define NXCD 8
#define SUBCAP 8960   // per-sub-bucket record capacity (mean 8192, sigma~90 -> 8.5 sigma slack)

// ---------------------------------------------------------------------------
// Register-tiled GEMM + fused attention logits.
//   H[n,64] = X[n,K] @ W[K,64];  As[n] = H.att_s;  Ad[n] = H.att_d
// Block: 256 threads -> tile 64 nodes x 64 features, per-thread 4x4 acc.
// ---------------------------------------------------------------------------
template <int K>
__global__ __launch_bounds__(256) void gemm_tile(
    const float* __restrict__ X, const float* __restrict__ W,
    const float* __restrict__ att_s, const float* __restrict__ att_d,
    float* __restrict__ H, float* __restrict__ As, float* __restrict__ Ad,
    int n)
{
    constexpr int XP = K + 4;
    constexpr int BK = 64;
    __shared__ float Xs[64 * XP];
    __shared__ float Ws[BK * 64];

    const int tid = threadIdx.x;
    const int node0 = blockIdx.x * 64;

    for (int i4 = tid; i4 < 64 * (K / 4); i4 += 256) {
        int r = i4 / (K / 4);
        int c = (i4 % (K / 4)) * 4;
        int nd = node0 + r;
        float4 v = make_float4(0.f, 0.f, 0.f, 0.f);
        if (nd < n) v = *(const float4*)&X[(size_t)nd * K + c];
        *(float4*)&Xs[r * XP + c] = v;
    }

    const int tx = tid & 15;   // feature group
    const int ty = tid >> 4;   // node group

    float acc[4][4];
#pragma unroll
    for (int r = 0; r < 4; ++r)
#pragma unroll
        for (int f = 0; f < 4; ++f) acc[r][f] = 0.0f;

    for (int kc = 0; kc < K; kc += BK) {
        __syncthreads();
        for (int i = tid; i < BK * 64; i += 256) Ws[i] = W[kc * 64 + i];
        __syncthreads();

        for (int k = 0; k < BK; k += 4) {
            float4 a0 = *(const float4*)&Xs[(ty * 4 + 0) * XP + kc + k];
            float4 a1 = *(const float4*)&Xs[(ty * 4 + 1) * XP + kc + k];
            float4 a2 = *(const float4*)&Xs[(ty * 4 + 2) * XP + kc + k];
            float4 a3 = *(const float4*)&Xs[(ty * 4 + 3) * XP + kc + k];
            float4 b0 = *(const float4*)&Ws[(k + 0) * 64 + tx * 4];
            float4 b1 = *(const float4*)&Ws[(k + 1) * 64 + tx * 4];
            float4 b2 = *(const float4*)&Ws[(k + 2) * 64 + tx * 4];
            float4 b3 = *(const float4*)&Ws[(k + 3) * 64 + tx * 4];
#define GEMM_ROW(rr, av)                                                     \
            acc[rr][0] = fmaf(av.x, b0.x, acc[rr][0]);                       \
            acc[rr][1] = fmaf(av.x, b0.y, acc[rr][1]);                       \
            acc[rr][2] = fmaf(av.x, b0.z, acc[rr][2]);                       \
            acc[rr][3] = fmaf(av.x, b0.w, acc[rr][3]);                       \
            acc[rr][0] = fmaf(av.y, b1.x, acc[rr][0]);                       \
            acc[rr][1] = fmaf(av.y, b1.y, acc[rr][1]);                       \
            acc[rr][2] = fmaf(av.y, b1.z, acc[rr][2]);                       \
            acc[rr][3] = fmaf(av.y, b1.w, acc[rr][3]);                       \
            acc[rr][0] = fmaf(av.z, b2.x, acc[rr][0]);                       \
            acc[rr][1] = fmaf(av.z, b2.y, acc[rr][1]);                       \
            acc[rr][2] = fmaf(av.z, b2.z, acc[rr][2]);                       \
            acc[rr][3] = fmaf(av.z, b2.w, acc[rr][3]);                       \
            acc[rr][0] = fmaf(av.w, b3.x, acc[rr][0]);                       \
            acc[rr][1] = fmaf(av.w, b3.y, acc[rr][1]);                       \
            acc[rr][2] = fmaf(av.w, b3.z, acc[rr][2]);                       \
            acc[rr][3] = fmaf(av.w, b3.w, acc[rr][3]);
            GEMM_ROW(0, a0)
            GEMM_ROW(1, a1)
            GEMM_ROW(2, a2)
            GEMM_ROW(3, a3)
#undef GEMM_ROW
        }
    }

    float4 ats = *(const float4*)&att_s[tx * 4];
    float4 atd = *(const float4*)&att_d[tx * 4];
#pragma unroll
    for (int rr = 0; rr < 4; ++rr) {
        int nd = node0 + ty * 4 + rr;
        float vs = acc[rr][0] * ats.x + acc[rr][1] * ats.y +
                   acc[rr][2] * ats.z + acc[rr][3] * ats.w;
        float vd = acc[rr][0] * atd.x + acc[rr][1] * atd.y +
                   acc[rr][2] * atd.z + acc[rr][3] * atd.w;
#pragma unroll
        for (int off = 8; off; off >>= 1) {
            vs += __shfl_xor(vs, off);
            vd += __shfl_xor(vd, off);
        }
        if (nd < n) {
            float4 hv = make_float4(acc[rr][0], acc[rr][1], acc[rr][2], acc[rr][3]);
            *(float4*)&H[(size_t)nd * 64 + tx * 4] = hv;
            if (tx == 0) { As[nd] = vs; Ad[nd] = vd; }
        }
    }
}

// ---------------------------------------------------------------------------
// Level 1: fine bucketing into sub-buckets of 512 dst nodes (sub = d >> 9).
// LDS histogram + one global atomic per (block, sub-bucket) reservation +
// LDS-cursor compacted writes of 4B packed records ((d&511)<<17 | src).
// ZERO per-edge global atomics. Requires n <= 131072 (nsub <= 256) and
// src < 2^17 (n=100000 ok).
// ---------------------------------------------------------------------------
__global__ __launch_bounds__(256) void fbucket_kernel(
    const int* __restrict__ src, const int* __restrict__ dst, int e,
    int* __restrict__ gcnt /* stride 16 ints */, unsigned* __restrict__ bkt)
{
    __shared__ int cnt[256];
    __shared__ int off[256];
    const int tid = threadIdx.x;
    const int chunk = (e + gridDim.x - 1) / gridDim.x;
    const int beg = blockIdx.x * chunk;
    const int end = min(beg + chunk, e);

    cnt[tid] = 0;
    __syncthreads();

    // pass A: LDS sub-bucket histogram
    for (int i = beg + tid; i < end; i += 256)
        atomicAdd(&cnt[dst[i] >> 9], 1);
    __syncthreads();

    // per-(block, sub) reservation: one global atomic each (64B-padded counters)
    {
        int c = cnt[tid];
        off[tid] = tid * SUBCAP + (c ? atomicAdd(&gcnt[tid * 16], c) : 0);
    }
    __syncthreads();

    // pass B: LDS-cursor compacted writes (chunk is L2-hot from pass A)
    for (int i = beg + tid; i < end; i += 256) {
        int d = dst[i];
        int s = src[i];
        int sub = d >> 9;
        int pos = atomicAdd(&off[sub], 1);
        if (pos < (sub + 1) * SUBCAP)
            bkt[pos] = ((unsigned)(d & 511) << 17) | (unsigned)s;
    }
}

// ---------------------------------------------------------------------------
// Level 2: one block per sub-bucket. Load records to LDS, LDS histogram over
// 512 node counters, block-wide exclusive scan, LDS-cursor placement ->
// dst-sorted rec (ev computed here; Ad slice in LDS) + per-node (beg,end).
// Zero global atomics; block exclusively owns its 70KB rec region -> L2
// write-combining is perfect (every line fully written).
// ---------------------------------------------------------------------------
__global__ __launch_bounds__(256) void sort3_kernel(
    const unsigned* __restrict__ bkt, const int* __restrict__ gcnt,
    const float* __restrict__ As, const float* __restrict__ Ad,
    int2* __restrict__ rec, int2* __restrict__ rpBE, int n)
{
    __shared__ unsigned recs[SUBCAP];  // 35840 B
    __shared__ int hist[512];          // counts -> exclusive offsets -> cursors
    __shared__ float AdS[512];
    __shared__ int sh[256];

    const int b = blockIdx.x;
    const int tid = threadIdx.x;
    const int base = b * SUBCAP;
    const int cnt = min(gcnt[b * 16], SUBCAP);

    for (int t = tid; t < 512; t += 256) {
        hist[t] = 0;
        int d = (b << 9) + t;
        AdS[t] = (d < n) ? Ad[d] : 0.0f;
    }
    __syncthreads();

    // load + histogram
    for (int i = tid; i < cnt; i += 256) {
        unsigned v = bkt[base + i];
        recs[i] = v;
        atomicAdd(&hist[v >> 17], 1);
    }
    __syncthreads();

    // 512-entry exclusive scan (2 elems/thread)
    int a0 = hist[2 * tid];
    int a1 = hist[2 * tid + 1];
    sh[tid] = a0 + a1;
    __syncthreads();
    for (int off = 1; off < 256; off <<= 1) {
        int x = (tid >= off) ? sh[tid - off] : 0;
        __syncthreads();
        sh[tid] += x;
        __syncthreads();
    }
    int ex = (tid > 0) ? sh[tid - 1] : 0;
    hist[2 * tid]     = ex;            // becomes placement cursor
    hist[2 * tid + 1] = ex + a0;
    {
        int d0 = (b << 9) + 2 * tid;
        if (d0 < n)     rpBE[d0]     = make_int2(base + ex,          base + ex + a0);
        if (d0 + 1 < n) rpBE[d0 + 1] = make_int2(base + ex + a0,     base + ex + a0 + a1);
    }
    __syncthreads();

    // placement: sorted rec with fused leaky-relu logit
    for (int i = tid; i < cnt; i += 256) {
        unsigned v = recs[i];
        int dl = (int)(v >> 17);
        int s  = (int)(v & 0x1FFFFu);
        int pos = atomicAdd(&hist[dl], 1);
        float ev = As[s] + AdS[dl];
        ev = (ev >= 0.0f) ? ev : NEG_SLOPE * ev;
        rec[base + pos] = make_int2(s, __float_as_int(ev));
    }
}

// ---------------------------------------------------------------------------
// Aggregation: one wave per destination node, XCD-swizzled dst partition.
// Fast path (deg <= 64, ~always for Poisson(16)): records loaded ONCE, one
// edge per lane -> plain max butterfly, ONE vector expf for all edges, sum
// butterfly; gather loop pulls weight/src via shfl broadcast (LDS pipe, not
// VALU), softmax scale deferred to one multiply at the end. Eliminates all
// per-edge transcendentals and the second rec pass.
// ---------------------------------------------------------------------------
__global__ __launch_bounds__(256) void aggr_kernel(
    const int2* __restrict__ rpBE, const int2* __restrict__ rec,
    const float* __restrict__ Hin, const float* __restrict__ bias,
    float* __restrict__ Out, int n, int lo_div, int relu_flag)
{
    const int lane = threadIdx.x & 63;
    const int wv = threadIdx.x >> 6;
    const float b = bias[lane];

    const int g = blockIdx.x & (NXCD - 1);
    const int gi = blockIdx.x >> 3;
    const int ngb = gridDim.x >> 3;
    const int lo = g * lo_div;
    const int hi = min(lo + lo_div, n);

    for (int d = lo + gi * 4 + wv; d < hi; d += ngb * 4) {
        const int2 be = rpBE[d];
        const int beg = be.x;
        const int deg = be.y - be.x;
        float r;

        if (deg <= 64) {
            // ---- lane-resident softmax ----
            int   si = 0;
            float ei = -1e30f;
            if (lane < deg) {
                int2 rc = rec[beg + lane];
                si = rc.x;
                ei = __int_as_float(rc.y);
            }
            float m = ei;
#pragma unroll
            for (int off = 32; off; off >>= 1) m = fmaxf(m, __shfl_xor(m, off));
            float ex = (lane < deg) ? __expf(ei - m) : 0.0f;
            float s = ex;
#pragma unroll
            for (int off = 32; off; off >>= 1) s += __shfl_xor(s, off);
            const float inv = 1.0f / (s + 1e-16f);

            // ---- gather: w/src broadcast from lanes, scale deferred ----
            float a0 = 0.f, a1 = 0.f, a2 = 0.f, a3 = 0.f;
            int i = 0;
            for (; i + 4 <= deg; i += 4) {
                int   s0 = __shfl(si, i + 0), s1 = __shfl(si, i + 1);
                int   s2 = __shfl(si, i + 2), s3 = __shfl(si, i + 3);
                float w0 = __shfl(ex, i + 0), w1 = __shfl(ex, i + 1);
                float w2 = __shfl(ex, i + 2), w3 = __shfl(ex, i + 3);
                a0 = fmaf(w0, Hin[(size_t)s0 * 64 + lane], a0);
                a1 = fmaf(w1, Hin[(size_t)s1 * 64 + lane], a1);
                a2 = fmaf(w2, Hin[(size_t)s2 * 64 + lane], a2);
                a3 = fmaf(w3, Hin[(size_t)s3 * 64 + lane], a3);
            }
            for (; i < deg; ++i) {
                int   s0 = __shfl(si, i);
                float w0 = __shfl(ex, i);
                a0 = fmaf(w0, Hin[(size_t)s0 * 64 + lane], a0);
            }
            r = ((a0 + a1) + (a2 + a3)) * inv + b;
        } else {
            // ---- fallback: two-pass online softmax (rare) ----
            const int end = beg + deg;
            float m = -1e30f, s = 0.0f;
            for (int i = beg + lane; i < end; i += 64) {
                float e = __int_as_float(rec[i].y);
                float mn = fmaxf(m, e);
                s = s * __expf(m - mn) + __expf(e - mn);
                m = mn;
            }
#pragma unroll
            for (int off = 32; off; off >>= 1) {
                float mo = __shfl_xor(m, off);
                float so = __shfl_xor(s, off);
                float mn = fmaxf(m, mo);
                s = s * __expf(m - mn) + so * __expf(mo - mn);
                m = mn;
            }
            const float inv = 1.0f / (s + 1e-16f);

            float a0 = 0.f, a1 = 0.f, a2 = 0.f, a3 = 0.f;
            int i = beg;
            for (; i + 4 <= end; i += 4) {
                int2 r0 = rec[i + 0];
                int2 r1 = rec[i + 1];
                int2 r2 = rec[i + 2];
                int2 r3 = rec[i + 3];
                float w0 = __expf(__int_as_float(r0.y) - m) * inv;
                float w1 = __expf(__int_as_float(r1.y) - m) * inv;
                float w2 = __expf(__int_as_float(r2.y) - m) * inv;
                float w3 = __expf(__int_as_float(r3.y) - m) * inv;
                a0 = fmaf(w0, Hin[(size_t)r0.x * 64 + lane], a0);
                a1 = fmaf(w1, Hin[(size_t)r1.x * 64 + lane], a1);
                a2 = fmaf(w2, Hin[(size_t)r2.x * 64 + lane], a2);
                a3 = fmaf(w3, Hin[(size_t)r3.x * 64 + lane], a3);
            }
            for (; i < end; ++i) {
                int2 rr = rec[i];
                float w = __expf(__int_as_float(rr.y) - m) * inv;
                a0 = fmaf(w, Hin[(size_t)rr.x * 64 + lane], a0);
            }
            r = (a0 + a1) + (a2 + a3) + b;
        }

        if (relu_flag) r = fmaxf(r, 0.0f);
        Out[(size_t)d * 64 + lane] = r;
    }
}

// ---------------------------------------------------------------------------
// Final linear [64 -> 32] + log_softmax. 2 nodes per wave.
// ---------------------------------------------------------------------------
__global__ __launch_bounds__(256) void lin_lsm_kernel(
    const float* __restrict__ Z, const float* __restrict__ Wl,
    const float* __restrict__ bl, float* __restrict__ out, int n)
{
    __shared__ float Ws[64 * 32];
    __shared__ float bs[32];
    for (int i = threadIdx.x; i < 64 * 32; i += 256) Ws[i] = Wl[i];
    if (threadIdx.x < 32) bs[threadIdx.x] = bl[threadIdx.x];
    __syncthreads();

    const int lane = threadIdx.x & 63;
    const int wv = threadIdx.x >> 6;
    const int half = lane >> 5;
    const int o = lane & 31;

    for (int base = (blockIdx.x * 4 + wv) * 2; base < n; base += gridDim.x * 8) {
        const int nd = base + half;
        float acc = 0.0f;
        if (nd < n) {
            const float* z = Z + (size_t)nd * 64;
#pragma unroll
            for (int k = 0; k < 64; ++k)
                acc = fmaf(z[k], Ws[k * 32 + o], acc);
            acc += bs[o];
        }
        float m = acc;
#pragma unroll
        for (int off = 16; off; off >>= 1) m = fmaxf(m, __shfl_xor(m, off, 32));
        float ex = __expf(acc - m);
        float s = ex;
#pragma unroll
        for (int off = 16; off; off >>= 1) s += __shfl_xor(s, off, 32);
        if (nd < n) out[(size_t)nd * 32 + o] = acc - m - logf(s);
    }
}

// ---------------------------------------------------------------------------
extern "C" void kernel_launch(void* const* d_in, const int* in_sizes, int n_in,
                              void* d_out, int out_size, void* d_ws, size_t ws_size,
                              hipStream_t stream)
{
    const float* x        = (const float*)d_in[0];
    const int*   ei1      = (const int*)d_in[1];
    const int*   ei2      = (const int*)d_in[2];
    const float* W1       = (const float*)d_in[3];
    const float* att_src1 = (const float*)d_in[4];
    const float* att_dst1 = (const float*)d_in[5];
    const float* b1       = (const float*)d_in[6];
    const float* W2       = (const float*)d_in[7];
    const float* att_src2 = (const float*)d_in[8];
    const float* att_dst2 = (const float*)d_in[9];
    const float* b2       = (const float*)d_in[10];
    const float* Wlin     = (const float*)d_in[11];
    const float* blin     = (const float*)d_in[12];
    float* out = (float*)d_out;

    const int n = in_sizes[0] / 128;   // 100000
    const int e = in_sizes[1] / 2;     // 1600000
    const int nsub = (n + 511) >> 9;   // 196 sub-buckets of 512 nodes

    size_t off = 0;
    auto alloc = [&](size_t bytes) {
        void* p = (char*)d_ws + off;
        off += (bytes + 255) & ~(size_t)255;
        return p;
    };
    float* bufH  = (float*)alloc((size_t)n * 64 * 4);
    float* bufZ  = (float*)alloc((size_t)n * 64 * 4);
    float* As    = (float*)alloc((size_t)n * 4);
    float* Ad    = (float*)alloc((size_t)n * 4);
    int2* rpBE   = (int2*)alloc((size_t)n * 8);
    int* gcnt    = (int*)alloc((size_t)256 * 16 * 4);      // 64B-padded counters
    int2* rec    = (int2*)alloc((size_t)nsub * SUBCAP * 8);

    unsigned* bkt = (unsigned*)bufZ;   // 7.0 MB packed records overlay bufZ (dead here)

    const int lo_div = (n + NXCD - 1) / NXCD;
    const int gTile = (n + 63) / 64;
    const int gAggr = NXCD * ((lo_div + 3) / 4);
    const int gBkt  = 512;             // chunk ~3125 edges/block

    // ---------------- Layer 1 ----------------
    gemm_tile<128><<<gTile, 256, 0, stream>>>(x, W1, att_src1, att_dst1, bufH, As, Ad, n);

    hipMemsetAsync(gcnt, 0, (size_t)256 * 16 * 4, stream);
    fbucket_kernel<<<gBkt, 256, 0, stream>>>(ei1, ei1 + e, e, gcnt, bkt);
    sort3_kernel<<<nsub, 256, 0, stream>>>(bkt, gcnt, As, Ad, rec, rpBE, n);
    aggr_kernel<<<gAggr, 256, 0, stream>>>(rpBE, rec, bufH, b1, bufZ, n, lo_div, 1);

    // ---------------- Layer 2 ----------------
    gemm_tile<64><<<gTile, 256, 0, stream>>>(bufZ, W2, att_src2, att_dst2, bufH, As, Ad, n);

    hipMemsetAsync(gcnt, 0, (size_t)256 * 16 * 4, stream);
    fbucket_kernel<<<gBkt, 256, 0, stream>>>(ei2, ei2 + e, e, gcnt, bkt);
    sort3_kernel<<<nsub, 256, 0, stream>>>(bkt, gcnt, As, Ad, rec, rpBE, n);
    aggr_kernel<<<gAggr, 256, 0, stream>>>(rpBE, rec, bufH, b2, bufZ, n, lo_div, 0);

    // ---------------- Final linear + log_softmax ----------------
    const int gLSM = (n + 7) / 8;
    lin_lsm_kernel<<<gLSM, 256, 0, stream>>>(bufZ, Wlin, blin, out, n);
}